// Round 1
// baseline (970.480 us; speedup 1.0000x reference)
//
#include <hip/hip_runtime.h>

// LeNet C3 sparse conv: x[32,6,512,512] f32, w[16,6,5,5] f32 (masked by
// connectivity), bias[16] -> out[32,16,508,508] f32, VALID 5x5.
//
// Strategy (round 1 baseline): fp32 direct conv.
//  - block 256 thr, tile 64x16 outputs, one image; grid (8,32,32)
//  - input halo tile (6 x 20 x 68 f32 = 32.6 KB) + weights re-laid out
//    [ic][kh][oc][8] (15.4 KB) staged in LDS, single barrier
//  - thread = 4 consecutive output cols x all 16 oc -> acc[16][4] regs
//  - compile-time inverse connectivity (each ic feeds exactly 10 ocs)
//    skips masked pairs: 60/96 of dense FLOPs
//  - per (kh,ic): 2x ds_read_b128 -> 8 inputs reused for 200 FMAs

#define TILE_W 64
#define TILE_H 16
#define IN_W   (TILE_W + 4)   // 68
#define IN_H   (TILE_H + 4)   // 20

__global__ __launch_bounds__(256, 3) void c3_kernel(
    const float* __restrict__ x, const float* __restrict__ wgt,
    const float* __restrict__ bias, float* __restrict__ out)
{
    constexpr int IC = 6, OC = 16, H = 512, W = 512, OH = 508, OW = 508;
    // inverse of MAP_S2: for each input channel, the 10 output maps it feeds
    static constexpr int CONN[6][10] = {
        {0, 4, 5, 6, 9, 10, 11, 12, 14, 15},
        {0, 1, 5, 6, 7, 10, 11, 12, 13, 15},
        {0, 1, 2, 6, 7, 8, 11, 13, 14, 15},
        {1, 2, 3, 6, 7, 8, 9, 12, 14, 15},
        {2, 3, 4, 7, 8, 9, 10, 12, 13, 15},
        {3, 4, 5, 8, 9, 10, 11, 13, 14, 15}};

    __shared__ __align__(16) float xs[IC][IN_H][IN_W];   // 32640 B
    __shared__ __align__(16) float ws[IC][5][OC][8];     // 15360 B (kw padded 5->8)

    const int tid = threadIdx.x;
    const int ow0 = blockIdx.x * TILE_W;
    const int oh0 = blockIdx.y * TILE_H;
    const int n   = blockIdx.z;

    // ---- stage weights: wgt[oc][ic][kh][kw] -> ws[ic][kh][oc][kw]
    for (int i = tid; i < OC * IC * 25; i += 256) {
        const int oc = i / 150;
        const int rem = i % 150;
        const int ic = rem / 25;
        const int kh = (rem % 25) / 5;
        const int kw = rem % 5;
        ws[ic][kh][oc][kw] = wgt[i];
    }

    // ---- stage input halo tile (float4 loads, clamp rows, zero OOB cols)
    const float* xn = x + (size_t)n * IC * H * W;
    for (int i = tid; i < IC * IN_H * (IN_W / 4); i += 256) {
        const int ic  = i / (IN_H * 17);
        const int rem = i % (IN_H * 17);
        const int r   = rem / 17;
        const int c4  = (rem % 17) * 4;
        int h = oh0 + r; if (h > H - 1) h = H - 1;   // clamped rows only feed discarded outputs
        const int wc = ow0 + c4;
        float4 v;
        if (wc <= W - 4) {
            v = *(const float4*)(xn + ((size_t)ic * H + h) * W + wc);
        } else {
            v = make_float4(0.f, 0.f, 0.f, 0.f);
        }
        *(float4*)&xs[ic][r][c4] = v;
    }
    __syncthreads();

    // ---- compute: thread -> (row, 4-col group), all 16 oc
    const int row = tid >> 4;        // 0..15
    const int c0  = (tid & 15) * 4;  // 0..60

    float acc[OC][4];
    #pragma unroll
    for (int oc = 0; oc < OC; ++oc)
        #pragma unroll
        for (int r = 0; r < 4; ++r) acc[oc][r] = 0.f;

    #pragma unroll 1
    for (int kh = 0; kh < 5; ++kh) {
        #pragma unroll
        for (int ic = 0; ic < IC; ++ic) {
            float in[8];
            *(float4*)&in[0] = *(const float4*)&xs[ic][row + kh][c0];
            *(float4*)&in[4] = *(const float4*)&xs[ic][row + kh][c0 + 4];
            #pragma unroll
            for (int j = 0; j < 10; ++j) {
                const int oc = CONN[ic][j];
                float wv[5];
                *(float4*)&wv[0] = *(const float4*)&ws[ic][kh][oc][0];
                wv[4] = ws[ic][kh][oc][4];
                #pragma unroll
                for (int kw = 0; kw < 5; ++kw)
                    #pragma unroll
                    for (int r = 0; r < 4; ++r)
                        acc[oc][r] = fmaf(in[r + kw], wv[kw], acc[oc][r]);
            }
        }
    }

    // ---- store (+bias), float4 per oc
    const int oh = oh0 + row;
    const int ow = ow0 + c0;
    if (oh < OH && ow < OW) {
        float* op = out + (((size_t)n * OC) * OH + oh) * OW + ow;
        #pragma unroll
        for (int oc = 0; oc < OC; ++oc) {
            const float b = bias[oc];
            float4 v = make_float4(acc[oc][0] + b, acc[oc][1] + b,
                                   acc[oc][2] + b, acc[oc][3] + b);
            *(float4*)(op + (size_t)oc * OH * OW) = v;
        }
    }
}

extern "C" void kernel_launch(void* const* d_in, const int* in_sizes, int n_in,
                              void* d_out, int out_size, void* d_ws, size_t ws_size,
                              hipStream_t stream) {
    const float* x    = (const float*)d_in[0];
    const float* wgt  = (const float*)d_in[1];
    const float* bias = (const float*)d_in[2];
    float* out = (float*)d_out;
    dim3 grid((508 + TILE_W - 1) / TILE_W,   // 8
              (508 + TILE_H - 1) / TILE_H,   // 32
              32);
    c3_kernel<<<grid, dim3(256), 0, stream>>>(x, wgt, bias, out);
}